// Round 5
// baseline (184.410 us; speedup 1.0000x reference)
//
#include <hip/hip_runtime.h>
#include <stdint.h>

// Problem constants
#define B_   4
#define S_   2048
#define D_   1024
#define H_   16
#define HD_  64
#define BH_  (B_*H_)      // 64
#define M_   (B_*S_)      // 8192
#define KD_  1024         // GEMM K (= D)

typedef __bf16 bf16x8 __attribute__((ext_vector_type(8)));
typedef float f32x4 __attribute__((ext_vector_type(4)));
typedef float f32x16 __attribute__((ext_vector_type(16)));
typedef unsigned int u32x4 __attribute__((ext_vector_type(4)));

__device__ __forceinline__ unsigned short f2bf(float f) {
  unsigned int u = __float_as_uint(f);
  u = u + 0x7fffu + ((u >> 16) & 1u);   // RNE
  return (unsigned short)(u >> 16);
}

__device__ __forceinline__ void gload16(const void* g, void* lds) {
  __builtin_amdgcn_global_load_lds(
      (__attribute__((address_space(1))) void*)(g),
      (__attribute__((address_space(3))) void*)(lds),
      16, 0, 0);
}

__device__ __forceinline__ bf16x8 ldfrag(const unsigned short* p) {
  return *reinterpret_cast<const bf16x8*>(p);
}

__device__ __forceinline__ unsigned int cvtpk(float lo, float hi) {
  unsigned int r;
  asm("v_cvt_pk_bf16_f32 %0, %1, %2" : "=v"(r) : "v"(lo), "v"(hi));
  return r;
}

// v_permlane32_swap_b32: a's upper 32 lanes <-> b's lower 32 lanes.
__device__ __forceinline__ void plswap(unsigned int& a, unsigned int& b) {
  asm("v_permlane32_swap_b32 %0, %1" : "+v"(a), "+v"(b));
}

__device__ __forceinline__ float2 pkadd2(float2 a, float2 b) {
  float2 r;
  asm("v_pk_add_f32 %0, %1, %2" : "=v"(r) : "v"(a), "v"(b));
  return r;
}

__device__ __forceinline__ bf16x8 mkfrag(unsigned int a, unsigned int b,
                                         unsigned int c, unsigned int d) {
  union { unsigned int w[4]; bf16x8 v; } u;
  u.w[0] = a; u.w[1] = b; u.w[2] = c; u.w[3] = d;
  return u.v;
}

// ---------------- x: fp32 -> bf16, vectorized ----------------
__global__ __launch_bounds__(256) void xconv(const float* __restrict__ in,
                                             unsigned short* __restrict__ out) {
  const size_t i = (size_t)blockIdx.x * 256 + threadIdx.x;
  const float4* p = reinterpret_cast<const float4*>(in) + i * 2;
  float4 a = p[0], b = p[1];
  union { u32x4 v; unsigned short u[8]; } cv;
  cv.u[0] = f2bf(a.x); cv.u[1] = f2bf(a.y); cv.u[2] = f2bf(a.z); cv.u[3] = f2bf(a.w);
  cv.u[4] = f2bf(b.x); cv.u[5] = f2bf(b.y); cv.u[6] = f2bf(b.z); cv.u[7] = f2bf(b.w);
  *reinterpret_cast<u32x4*>(out + i * 8) = cv.v;
}

// ------------- weight transpose+convert: src[R][C] f32 -> dst[C][R] bf16 -------------
__global__ __launch_bounds__(256) void wtrans(const float* __restrict__ src,
                                              unsigned short* __restrict__ dst,
                                              int R, int C) {
  __shared__ float t[32][33];
  const int c0 = blockIdx.x * 32, r0 = blockIdx.y * 32;
  const int x = threadIdx.x & 31, y = threadIdx.x >> 5;
#pragma unroll
  for (int yy = y; yy < 32; yy += 8)
    t[yy][x] = src[(size_t)(r0 + yy) * C + c0 + x];
  __syncthreads();
#pragma unroll
  for (int yy = y; yy < 32; yy += 8)
    dst[(size_t)(c0 + yy) * R + r0 + x] = f2bf(t[x][yy]);
}

// Shared GEMM machinery: 128x128 tile, BK=32, 4 LDS buffers, 3-deep prefetch,
// single barrier per K-tile, counted vmcnt (12 steady / 8 / 4 / 0 tail).
#define GSTAGE(buf, kt) do {                                    \
    gload16(Ag + (kt),            &Al[buf][(w*32)*32]);         \
    gload16(Ag + 16*KD_ + (kt),   &Al[buf][(w*32+16)*32]);      \
    gload16(Bg + (kt),            &Bl[buf][(w*32)*32]);         \
    gload16(Bg + 16*KD_ + (kt),   &Bl[buf][(w*32+16)*32]);      \
  } while (0)

#define GEMM_ITER(T_, VM_)                                                    \
  {                                                                           \
    asm volatile("s_waitcnt vmcnt(" VM_ ")" ::: "memory");                    \
    __builtin_amdgcn_s_barrier();                                             \
    __builtin_amdgcn_sched_barrier(0);                                        \
    if ((T_) + 3 < 32) GSTAGE(((T_) + 3) & 3, ((T_) + 3) * 32);               \
    const unsigned short* Ab_ = &Al[(T_) & 3][0];                             \
    const unsigned short* Bb_ = &Bl[(T_) & 3][0];                             \
    bf16x8 af[4], bfr[4];                                                     \
    _Pragma("unroll")                                                         \
    for (int i_ = 0; i_ < 4; ++i_)                                            \
      af[i_] = ldfrag(&Ab_[(wr + i_ * 16 + c) * 32 + ((g ^ sA) << 3)]);       \
    _Pragma("unroll")                                                         \
    for (int j_ = 0; j_ < 4; ++j_)                                            \
      bfr[j_] = ldfrag(&Bb_[(wc + j_ * 16 + c) * 32 + ((g ^ sA) << 3)]);      \
    _Pragma("unroll")                                                         \
    for (int i_ = 0; i_ < 4; ++i_)                                            \
      _Pragma("unroll")                                                       \
      for (int j_ = 0; j_ < 4; ++j_)                                          \
        acc[i_][j_] = __builtin_amdgcn_mfma_f32_16x16x32_bf16(                \
            af[i_], bfr[j_], acc[i_][j_], 0, 0, 0);                           \
  }

// ------------- QKV GEMM -> Q/K [BH][S][64], V direct-transposed [BH][64][S] -------------
__global__ __launch_bounds__(256) void qkv_gemm(
    const unsigned short* __restrict__ A,    // [8192][1024] bf16 (x)
    const unsigned short* __restrict__ Bt,   // [3072][1024] bf16 (w_in^T)
    const float* __restrict__ bias,          // [3072]
    unsigned short* __restrict__ Qo,         // [BH][S][64], pre-scaled
    unsigned short* __restrict__ Ko,         // [BH][S][64]
    unsigned short* __restrict__ Vto)        // [BH][64][S]  (transposed)
{
  __shared__ unsigned short Al[4][128 * 32];
  __shared__ unsigned short Bl[4][128 * 32];
  const int tid = threadIdx.x;
  const int w = tid >> 6, l = tid & 63;
  const int g = l >> 4, c = l & 15;
  const int m0 = blockIdx.y * 128, n0 = blockIdx.x * 128;
  const int wr = (w >> 1) * 64, wc = (w & 1) * 64;

  f32x4 acc[4][4] = {};

  const int srow = w * 32 + (l >> 2);
  const int slc  = ((l & 3) ^ ((l >> 3) & 3)) * 8;
  const unsigned short* Ag = A  + (size_t)(m0 + srow) * KD_ + slc;
  const unsigned short* Bg = Bt + (size_t)(n0 + srow) * KD_ + slc;

  const int sA = (c >> 1) & 3;

  GSTAGE(0, 0);
  GSTAGE(1, 32);
  GSTAGE(2, 64);
  for (int t = 0; t < 29; ++t) GEMM_ITER(t, "12");
  GEMM_ITER(29, "8");
  GEMM_ITER(30, "4");
  GEMM_ITER(31, "0");

  if (n0 >= 2048) {
    // V: write directly transposed (4 consecutive tokens -> one 8B packed store).
#pragma unroll
    for (int i = 0; i < 4; ++i)
#pragma unroll
      for (int j = 0; j < 4; ++j) {
        const int ng = n0 + wc + j * 16 + c;
        const int n  = ng - 2048;
        const int hh = n >> 6, dim = n & 63;
        const int m  = m0 + wr + i * 16 + g * 4;
        const int bb = m >> 11, ss = m & 2047;
        const float bv = bias[ng];
        uint2 pk;
        pk.x = cvtpk(acc[i][j][0] + bv, acc[i][j][1] + bv);
        pk.y = cvtpk(acc[i][j][2] + bv, acc[i][j][3] + bv);
        *reinterpret_cast<uint2*>(
            &Vto[((size_t)(bb * H_ + hh) * HD_ + dim) * S_ + ss]) = pk;
      }
  } else {
#pragma unroll
    for (int i = 0; i < 4; ++i)
#pragma unroll
      for (int j = 0; j < 4; ++j)
#pragma unroll
        for (int r = 0; r < 4; ++r) {
          const int m = m0 + wr + i * 16 + g * 4 + r;
          const int n = n0 + wc + j * 16 + c;
          float v = acc[i][j][r] + bias[n];
          const int which = n >> 10;
          const int dp = n & 1023;
          const int hh = dp >> 6, dim = dp & 63;
          const int bb = m >> 11, ss = m & 2047;
          const size_t idx = ((size_t)(bb * H_ + hh) * S_ + ss) * HD_ + dim;
          // Q scale: 1/sqrt(hd) * log2(e)  (softmax runs in exp2 domain)
          if (which == 0) Qo[idx] = f2bf(v * 0.18033688f);
          else            Ko[idx] = f2bf(v);
        }
  }
}

// ------------- out GEMM: d_out = Ob @ w_out + b_out (fp32 out) -------------
__global__ __launch_bounds__(256) void out_gemm(
    const unsigned short* __restrict__ A,
    const unsigned short* __restrict__ Bt,
    const float* __restrict__ bias,
    float* __restrict__ C)
{
  __shared__ unsigned short Al[4][128 * 32];
  __shared__ unsigned short Bl[4][128 * 32];
  const int tid = threadIdx.x;
  const int w = tid >> 6, l = tid & 63;
  const int g = l >> 4, c = l & 15;
  const int m0 = blockIdx.y * 128, n0 = blockIdx.x * 128;
  const int wr = (w >> 1) * 64, wc = (w & 1) * 64;

  f32x4 acc[4][4] = {};

  const int srow = w * 32 + (l >> 2);
  const int slc  = ((l & 3) ^ ((l >> 3) & 3)) * 8;
  const unsigned short* Ag = A  + (size_t)(m0 + srow) * KD_ + slc;
  const unsigned short* Bg = Bt + (size_t)(n0 + srow) * KD_ + slc;

  const int sA = (c >> 1) & 3;

  GSTAGE(0, 0);
  GSTAGE(1, 32);
  GSTAGE(2, 64);
  for (int t = 0; t < 29; ++t) GEMM_ITER(t, "12");
  GEMM_ITER(29, "8");
  GEMM_ITER(30, "4");
  GEMM_ITER(31, "0");

#pragma unroll
  for (int i = 0; i < 4; ++i)
#pragma unroll
    for (int j = 0; j < 4; ++j)
#pragma unroll
      for (int r = 0; r < 4; ++r) {
        const int m = m0 + wr + i * 16 + g * 4 + r;
        const int n = n0 + wc + j * 16 + c;
        C[(size_t)m * D_ + n] = acc[i][j][r] + bias[n];
      }
}

// ------------- causal flash attention, no-max-sub softmax -------------
// 3 LDS buffers, 2-deep prefetch, single barrier per kv-tile, counted vmcnt(4).
// Each block processes q-tile pair (p, 15-p): exactly 34 kv-iterations.
__global__ __launch_bounds__(256) void attn_fwd5(
    const unsigned short* __restrict__ Q,   // [BH][S][64] (pre-scaled by 0.18033688)
    const unsigned short* __restrict__ Kg,  // [BH][S][64]
    const unsigned short* __restrict__ Vt,  // [BH][64][S]
    unsigned short* __restrict__ O)         // [B][S][1024] bf16
{
  __shared__ unsigned short Kl[3][64 * 64];
  __shared__ unsigned short Vl[3][64 * 64];

  const int tid = threadIdx.x;
  const int w = tid >> 6, l = tid & 63;
  const int q32 = l & 31, hi = l >> 5;

  // XCD-chunked swizzle: all 8 pair-blocks of one bh land on one XCD.
  const int raw = blockIdx.y * 8 + blockIdx.x;         // 0..511
  const int work = (raw & 7) * 64 + (raw >> 3);
  const int bh = work >> 3;
  const int p  = work & 7;
  const int q0A = p * 128;
  const int q0B = (15 - p) * 128;
  const int nA = 2 * (p + 1);                          // runtime
  // total = nA + nB = 34 always (compile-time)

  const unsigned short* Kbh = Kg + (size_t)bh * (S_ * HD_);
  const unsigned short* Vbh = Vt + (size_t)bh * (HD_ * S_);

  bf16x8 qf[4];
  auto loadQ = [&](int q0) {
    const unsigned short* Qrow = Q + ((size_t)bh * S_ + q0 + w * 32 + q32) * HD_ + hi * 8;
#pragma unroll
    for (int s = 0; s < 4; ++s) qf[s] = ldfrag(Qrow + s * 16);
  };

  f32x16 od0 = {}, od1 = {};
  float lrun = 0.f;

  const int krow = w * 16 + (l >> 3);
  const int slc = ((l & 7) ^ (l >> 3)) * 8;  // inverse-swizzled source chunk

#define LDSOFF(r, ch) ((r) * 64 + (((ch) ^ ((r) & 7)) << 3))

#define STAGE(buf, tile) do {                                                   \
    const int k0s = (tile) * 64;                                                \
    gload16(Kbh + (size_t)(k0s + krow) * HD_ + slc,     &Kl[buf][(w*16)*64]);   \
    gload16(Kbh + (size_t)(k0s + krow + 8) * HD_ + slc, &Kl[buf][(w*16+8)*64]); \
    gload16(Vbh + (size_t)krow * S_ + k0s + slc,        &Vl[buf][(w*16)*64]);   \
    gload16(Vbh + (size_t)(krow + 8) * S_ + k0s + slc,  &Vl[buf][(w*16+8)*64]); \
  } while (0)

  auto epilogue = [&](int q0) {
    const float rl = 1.0f / lrun;
    const int bb = bh >> 4, hh = bh & 15;
    const int sq = q0 + w * 32 + q32;
    unsigned short* Orow = O + ((size_t)bb * S_ + sq) * D_ + hh * HD_;
#pragma unroll
    for (int rr = 0; rr < 4; ++rr) {
      uint2 v0, v1;
      v0.x = cvtpk(od0[4 * rr] * rl,     od0[4 * rr + 1] * rl);
      v0.y = cvtpk(od0[4 * rr + 2] * rl, od0[4 * rr + 3] * rl);
      *reinterpret_cast<uint2*>(Orow + 8 * rr + 4 * hi) = v0;
      v1.x = cvtpk(od1[4 * rr] * rl,     od1[4 * rr + 1] * rl);
      v1.y = cvtpk(od1[4 * rr + 2] * rl, od1[4 * rr + 3] * rl);
      *reinterpret_cast<uint2*>(Orow + 32 + 8 * rr + 4 * hi) = v1;
    }
  };

  loadQ(q0A);
  STAGE(0, 0);
  STAGE(1, 1);
  int cur = 0;           // idx % 3
  int q0 = q0A;

  for (int idx = 0; idx < 34; ++idx) {
    const int kv = (idx < nA) ? idx : idx - nA;
    const int k0 = kv * 64;
    if (idx != 33) asm volatile("s_waitcnt vmcnt(4)" ::: "memory");
    else           asm volatile("s_waitcnt vmcnt(0)" ::: "memory");
    __builtin_amdgcn_s_barrier();
    __builtin_amdgcn_sched_barrier(0);

    // 2-ahead prefetch into buf (idx+2)%3 (its readers finished at iter idx-1).
    if (idx + 2 < 34) {
      const int i2 = idx + 2;
      const int nkv = (i2 < nA) ? i2 : i2 - nA;
      int sb = cur + 2; if (sb >= 3) sb -= 3;
      STAGE(sb, nkv);
    }

    const int wqmin = q0 + w * 32;
    if (k0 <= wqmin + 31) {   // wave-tile not fully masked
      const bool live1 = (k0 + 32 <= wqmin + 31);
      const unsigned short* Kb_ = &Kl[cur][0];
      const unsigned short* Vb_ = &Vl[cur][0];

      // ---- S^T = K x Q^T ----
      f32x16 st0 = {}, st1 = {};
      __builtin_amdgcn_s_setprio(1);
#pragma unroll
      for (int s = 0; s < 4; ++s) {
        bf16x8 kf = ldfrag(Kb_ + LDSOFF(q32, 2 * s + hi));
        st0 = __builtin_amdgcn_mfma_f32_32x32x16_bf16(kf, qf[s], st0, 0, 0, 0);
      }
      if (live1) {
#pragma unroll
        for (int s = 0; s < 4; ++s) {
          bf16x8 kf = ldfrag(Kb_ + LDSOFF(32 + q32, 2 * s + hi));
          st1 = __builtin_amdgcn_mfma_f32_32x32x16_bf16(kf, qf[s], st1, 0, 0, 0);
        }
      }
      __builtin_amdgcn_s_setprio(0);

      // ---- causal mask (diagonal region only) ----
      if (k0 + 63 > wqmin) {
        const int rel = wqmin + q32 - k0;
#pragma unroll
        for (int r = 0; r < 16; ++r) {
          const int kva = (r & 3) + 8 * (r >> 2) + 4 * hi;
          if (kva > rel) st0[r] = -1e30f;
        }
        if (live1) {
#pragma unroll
          for (int r = 0; r < 16; ++r) {
            const int kva = (r & 3) + 8 * (r >> 2) + 4 * hi;
            if (kva + 32 > rel) st1[r] = -1e30f;
          }
        }
      }

      // ---- p = exp2(st) directly; row-sum via packed f32 adds ----
      float2 e0[8], e1[8];
#pragma unroll
      for (int r = 0; r < 8; ++r) {
        e0[r].x = __builtin_amdgcn_exp2f(st0[2 * r]);
        e0[r].y = __builtin_amdgcn_exp2f(st0[2 * r + 1]);
      }
      float2 a0 = pkadd2(pkadd2(e0[0], e0[1]), pkadd2(e0[2], e0[3]));
      float2 a1 = pkadd2(pkadd2(e0[4], e0[5]), pkadd2(e0[6], e0[7]));
      float2 asum = pkadd2(a0, a1);
      if (live1) {
#pragma unroll
        for (int r = 0; r < 8; ++r) {
          e1[r].x = __builtin_amdgcn_exp2f(st1[2 * r]);
          e1[r].y = __builtin_amdgcn_exp2f(st1[2 * r + 1]);
        }
        float2 b0 = pkadd2(pkadd2(e1[0], e1[1]), pkadd2(e1[2], e1[3]));
        float2 b1 = pkadd2(pkadd2(e1[4], e1[5]), pkadd2(e1[6], e1[7]));
        asum = pkadd2(asum, pkadd2(b0, b1));
      }
      float ps = asum.x + asum.y;
      ps += __shfl_xor(ps, 32);
      lrun += ps;

      // ---- P -> bf16 A-frags via cvt_pk + permlane32_swap ----
      unsigned int W0, W1, W2, W3, W4, W5, W6, W7;
      W0 = cvtpk(e0[0].x, e0[0].y); W1 = cvtpk(e0[1].x, e0[1].y);
      W2 = cvtpk(e0[2].x, e0[2].y); W3 = cvtpk(e0[3].x, e0[3].y);
      W4 = cvtpk(e0[4].x, e0[4].y); W5 = cvtpk(e0[5].x, e0[5].y);
      W6 = cvtpk(e0[6].x, e0[6].y); W7 = cvtpk(e0[7].x, e0[7].y);
      plswap(W0, W2); plswap(W1, W3); plswap(W4, W6); plswap(W5, W7);
      const bf16x8 pa0 = mkfrag(W0, W1, W2, W3);
      const bf16x8 pa1 = mkfrag(W4, W5, W6, W7);
      bf16x8 pa2, pa3;
      if (live1) {
        W0 = cvtpk(e1[0].x, e1[0].y); W1 = cvtpk(e1[1].x, e1[1].y);
        W2 = cvtpk(e1[2].x, e1[2].y); W3 = cvtpk(e1[3].x, e1[3].y);
        W4 = cvtpk(e1[4].x, e1[4].y); W5 = cvtpk(e1[5].x, e1[5].y);
        W6 = cvtpk(e1[6].x, e1[6].y); W7 = cvtpk(e1[7].x, e1[7].y);
        plswap(W0, W2); plswap(W1, W3); plswap(W4, W6); plswap(W5, W7);
        pa2 = mkfrag(W0, W1, W2, W3);
        pa3 = mkfrag(W4, W5, W6, W7);
      }

      // ---- O^T += V^T x P^T ----
      __builtin_amdgcn_s_setprio(1);
#pragma unroll
      for (int s = 0; s < 2; ++s) {
        const bf16x8 pa = (s == 0) ? pa0 : pa1;
        bf16x8 vf = ldfrag(Vb_ + LDSOFF(q32, 2 * s + hi));
        od0 = __builtin_amdgcn_mfma_f32_32x32x16_bf16(vf, pa, od0, 0, 0, 0);
        bf16x8 vg = ldfrag(Vb_ + LDSOFF(32 + q32, 2 * s + hi));
        od1 = __builtin_amdgcn_mfma_f32_32x32x16_bf16(vg, pa, od1, 0, 0, 0);
      }
      if (live1) {
#pragma unroll
        for (int s = 2; s < 4; ++s) {
          const bf16x8 pa = (s == 2) ? pa2 : pa3;
          bf16x8 vf = ldfrag(Vb_ + LDSOFF(q32, 2 * s + hi));
          od0 = __builtin_amdgcn_mfma_f32_32x32x16_bf16(vf, pa, od0, 0, 0, 0);
          bf16x8 vg = ldfrag(Vb_ + LDSOFF(32 + q32, 2 * s + hi));
          od1 = __builtin_amdgcn_mfma_f32_32x32x16_bf16(vg, pa, od1, 0, 0, 0);
        }
      }
      __builtin_amdgcn_s_setprio(0);
    }

    // transition A -> B (register-only; no LDS hazard)
    if (idx == nA - 1) {
      epilogue(q0A);
      loadQ(q0B);
      od0 = {}; od1 = {};
      lrun = 0.f;
      q0 = q0B;
    }
    cur = (cur == 2) ? 0 : cur + 1;
  }

  epilogue(q0B);
#undef STAGE
#undef LDSOFF
}

extern "C" void kernel_launch(void* const* d_in, const int* in_sizes, int n_in,
                              void* d_out, int out_size, void* d_ws, size_t ws_size,
                              hipStream_t stream) {
  (void)in_sizes; (void)n_in; (void)out_size; (void)ws_size;
  const float* x     = (const float*)d_in[0];
  const float* w_in  = (const float*)d_in[1];
  const float* b_in  = (const float*)d_in[2];
  const float* w_out = (const float*)d_in[3];
  const float* b_out = (const float*)d_in[4];
  float* out = (float*)d_out;
  char* ws = (char*)d_ws;
  const size_t MB = 1024 * 1024;
  unsigned short* xb     = (unsigned short*)(ws);             // 16MB
  unsigned short* w_inb  = (unsigned short*)(ws + 16 * MB);   // 6MB
  unsigned short* w_outb = (unsigned short*)(ws + 22 * MB);   // 2MB
  unsigned short* Qb     = (unsigned short*)(ws + 24 * MB);   // 16MB
  unsigned short* Kb     = (unsigned short*)(ws + 40 * MB);   // 16MB
  unsigned short* Vt     = (unsigned short*)(ws + 56 * MB);   // 16MB (transposed V)
  unsigned short* Ob     = (unsigned short*)(ws + 72 * MB);   // 16MB

  xconv<<<4096, 256, 0, stream>>>(x, xb);
  wtrans<<<dim3(96, 32), 256, 0, stream>>>(w_in, w_inb, 1024, 3072);
  wtrans<<<dim3(32, 32), 256, 0, stream>>>(w_out, w_outb, 1024, 1024);
  qkv_gemm<<<dim3(24, 64), 256, 0, stream>>>(xb, w_inb, b_in, Qb, Kb, Vt);
  attn_fwd5<<<dim3(8, 64), 256, 0, stream>>>(Qb, Kb, Vt, Ob);
  out_gemm<<<dim3(8, 64), 256, 0, stream>>>(Ob, w_outb, b_out, out);
}

// Round 6
// 180.378 us; speedup vs baseline: 1.0224x; 1.0224x over previous
//
#include <hip/hip_runtime.h>
#include <stdint.h>

// Problem constants
#define B_   4
#define S_   2048
#define D_   1024
#define H_   16
#define HD_  64
#define BH_  (B_*H_)      // 64
#define M_   (B_*S_)      // 8192
#define KD_  1024         // GEMM K (= D)

typedef __bf16 bf16x8 __attribute__((ext_vector_type(8)));
typedef float f32x4 __attribute__((ext_vector_type(4)));
typedef float f32x16 __attribute__((ext_vector_type(16)));
typedef unsigned int u32x4 __attribute__((ext_vector_type(4)));

__device__ __forceinline__ unsigned short f2bf(float f) {
  unsigned int u = __float_as_uint(f);
  u = u + 0x7fffu + ((u >> 16) & 1u);   // RNE
  return (unsigned short)(u >> 16);
}

__device__ __forceinline__ void gload16(const void* g, void* lds) {
  __builtin_amdgcn_global_load_lds(
      (__attribute__((address_space(1))) void*)(g),
      (__attribute__((address_space(3))) void*)(lds),
      16, 0, 0);
}

__device__ __forceinline__ bf16x8 ldfrag(const unsigned short* p) {
  return *reinterpret_cast<const bf16x8*>(p);
}

__device__ __forceinline__ unsigned int cvtpk(float lo, float hi) {
  unsigned int r;
  asm("v_cvt_pk_bf16_f32 %0, %1, %2" : "=v"(r) : "v"(lo), "v"(hi));
  return r;
}

// v_permlane32_swap_b32: a's upper 32 lanes <-> b's lower 32 lanes.
__device__ __forceinline__ void plswap(unsigned int& a, unsigned int& b) {
  asm("v_permlane32_swap_b32 %0, %1" : "+v"(a), "+v"(b));
}

__device__ __forceinline__ float2 pkadd2(float2 a, float2 b) {
  float2 r;
  asm("v_pk_add_f32 %0, %1, %2" : "=v"(r) : "v"(a), "v"(b));
  return r;
}

__device__ __forceinline__ bf16x8 mkfrag(unsigned int a, unsigned int b,
                                         unsigned int c, unsigned int d) {
  union { unsigned int w[4]; bf16x8 v; } u;
  u.w[0] = a; u.w[1] = b; u.w[2] = c; u.w[3] = d;
  return u.v;
}

// ---------------- x: fp32 -> bf16, vectorized ----------------
__global__ __launch_bounds__(256) void xconv(const float* __restrict__ in,
                                             unsigned short* __restrict__ out) {
  const size_t i = (size_t)blockIdx.x * 256 + threadIdx.x;
  const float4* p = reinterpret_cast<const float4*>(in) + i * 2;
  float4 a = p[0], b = p[1];
  union { u32x4 v; unsigned short u[8]; } cv;
  cv.u[0] = f2bf(a.x); cv.u[1] = f2bf(a.y); cv.u[2] = f2bf(a.z); cv.u[3] = f2bf(a.w);
  cv.u[4] = f2bf(b.x); cv.u[5] = f2bf(b.y); cv.u[6] = f2bf(b.z); cv.u[7] = f2bf(b.w);
  *reinterpret_cast<u32x4*>(out + i * 8) = cv.v;
}

// ------------- weight transpose+convert: src[R][C] f32 -> dst[C][R] bf16 -------------
__global__ __launch_bounds__(256) void wtrans(const float* __restrict__ src,
                                              unsigned short* __restrict__ dst,
                                              int R, int C) {
  __shared__ float t[32][33];
  const int c0 = blockIdx.x * 32, r0 = blockIdx.y * 32;
  const int x = threadIdx.x & 31, y = threadIdx.x >> 5;
#pragma unroll
  for (int yy = y; yy < 32; yy += 8)
    t[yy][x] = src[(size_t)(r0 + yy) * C + c0 + x];
  __syncthreads();
#pragma unroll
  for (int yy = y; yy < 32; yy += 8)
    dst[(size_t)(c0 + yy) * R + r0 + x] = f2bf(t[x][yy]);
}

// Shared GEMM machinery: 128x128 tile, BK=32, 3 LDS buffers (48KB), 2-deep
// prefetch, single barrier per K-tile, counted vmcnt(4) steady state.
// Iter t: vmcnt(4)+lgkmcnt(0) [stage t landed, t+1 in flight] -> barrier ->
// issue stage(t+2) [its buf's readers finished at t-1, before this barrier]
// -> ds_read(t) -> 16 MFMA. Issue-to-wait distance: 2 full iterations.
#define GSTAGE(buf, kt) do {                                    \
    gload16(Ag + (kt),            &Al[buf][(w*32)*32]);         \
    gload16(Ag + 16*KD_ + (kt),   &Al[buf][(w*32+16)*32]);      \
    gload16(Bg + (kt),            &Bl[buf][(w*32)*32]);         \
    gload16(Bg + 16*KD_ + (kt),   &Bl[buf][(w*32+16)*32]);      \
  } while (0)

#define GEMM_ITER(T_)                                                         \
  {                                                                           \
    if ((T_) == 31)                                                           \
      asm volatile("s_waitcnt vmcnt(0) lgkmcnt(0)" ::: "memory");             \
    else                                                                      \
      asm volatile("s_waitcnt vmcnt(4) lgkmcnt(0)" ::: "memory");             \
    __builtin_amdgcn_s_barrier();                                             \
    __builtin_amdgcn_sched_barrier(0);                                        \
    if ((T_) + 2 < 32) GSTAGE(((T_) + 2) % 3, ((T_) + 2) * 32);               \
    const unsigned short* Ab_ = &Al[(T_) % 3][0];                             \
    const unsigned short* Bb_ = &Bl[(T_) % 3][0];                             \
    bf16x8 af[4], bfr[4];                                                     \
    _Pragma("unroll")                                                         \
    for (int i_ = 0; i_ < 4; ++i_)                                            \
      af[i_] = ldfrag(&Ab_[(wr + i_ * 16 + c) * 32 + ((g ^ sA) << 3)]);       \
    _Pragma("unroll")                                                         \
    for (int j_ = 0; j_ < 4; ++j_)                                            \
      bfr[j_] = ldfrag(&Bb_[(wc + j_ * 16 + c) * 32 + ((g ^ sA) << 3)]);      \
    _Pragma("unroll")                                                         \
    for (int i_ = 0; i_ < 4; ++i_)                                            \
      _Pragma("unroll")                                                       \
      for (int j_ = 0; j_ < 4; ++j_)                                          \
        acc[i_][j_] = __builtin_amdgcn_mfma_f32_16x16x32_bf16(                \
            af[i_], bfr[j_], acc[i_][j_], 0, 0, 0);                           \
  }

// ------------- QKV GEMM -> Q/K [BH][S][64], V direct-transposed [BH][64][S] -------------
__global__ __launch_bounds__(256) void qkv_gemm(
    const unsigned short* __restrict__ A,    // [8192][1024] bf16 (x)
    const unsigned short* __restrict__ Bt,   // [3072][1024] bf16 (w_in^T)
    const float* __restrict__ bias,          // [3072]
    unsigned short* __restrict__ Qo,         // [BH][S][64], pre-scaled
    unsigned short* __restrict__ Ko,         // [BH][S][64]
    unsigned short* __restrict__ Vto)        // [BH][64][S]  (transposed)
{
  __shared__ unsigned short Al[3][128 * 32];
  __shared__ unsigned short Bl[3][128 * 32];
  const int tid = threadIdx.x;
  const int w = tid >> 6, l = tid & 63;
  const int g = l >> 4, c = l & 15;
  const int m0 = blockIdx.y * 128, n0 = blockIdx.x * 128;
  const int wr = (w >> 1) * 64, wc = (w & 1) * 64;

  f32x4 acc[4][4] = {};

  const int srow = w * 32 + (l >> 2);
  const int slc  = ((l & 3) ^ ((l >> 3) & 3)) * 8;
  const unsigned short* Ag = A  + (size_t)(m0 + srow) * KD_ + slc;
  const unsigned short* Bg = Bt + (size_t)(n0 + srow) * KD_ + slc;

  const int sA = (c >> 1) & 3;

  GSTAGE(0, 0);
  GSTAGE(1, 32);
#pragma unroll
  for (int t = 0; t < 32; ++t) GEMM_ITER(t);

  if (n0 >= 2048) {
    // V: write directly transposed (4 consecutive tokens -> one 8B packed store).
#pragma unroll
    for (int i = 0; i < 4; ++i)
#pragma unroll
      for (int j = 0; j < 4; ++j) {
        const int ng = n0 + wc + j * 16 + c;
        const int n  = ng - 2048;
        const int hh = n >> 6, dim = n & 63;
        const int m  = m0 + wr + i * 16 + g * 4;
        const int bb = m >> 11, ss = m & 2047;
        const float bv = bias[ng];
        uint2 pk;
        pk.x = cvtpk(acc[i][j][0] + bv, acc[i][j][1] + bv);
        pk.y = cvtpk(acc[i][j][2] + bv, acc[i][j][3] + bv);
        *reinterpret_cast<uint2*>(
            &Vto[((size_t)(bb * H_ + hh) * HD_ + dim) * S_ + ss]) = pk;
      }
  } else {
#pragma unroll
    for (int i = 0; i < 4; ++i)
#pragma unroll
      for (int j = 0; j < 4; ++j)
#pragma unroll
        for (int r = 0; r < 4; ++r) {
          const int m = m0 + wr + i * 16 + g * 4 + r;
          const int n = n0 + wc + j * 16 + c;
          float v = acc[i][j][r] + bias[n];
          const int which = n >> 10;
          const int dp = n & 1023;
          const int hh = dp >> 6, dim = dp & 63;
          const int bb = m >> 11, ss = m & 2047;
          const size_t idx = ((size_t)(bb * H_ + hh) * S_ + ss) * HD_ + dim;
          // Q scale: 1/sqrt(hd) * log2(e)  (softmax runs in exp2 domain)
          if (which == 0) Qo[idx] = f2bf(v * 0.18033688f);
          else            Ko[idx] = f2bf(v);
        }
  }
}

// ------------- out GEMM: d_out = Ob @ w_out + b_out (fp32 out) -------------
__global__ __launch_bounds__(256) void out_gemm(
    const unsigned short* __restrict__ A,
    const unsigned short* __restrict__ Bt,
    const float* __restrict__ bias,
    float* __restrict__ C)
{
  __shared__ unsigned short Al[3][128 * 32];
  __shared__ unsigned short Bl[3][128 * 32];
  const int tid = threadIdx.x;
  const int w = tid >> 6, l = tid & 63;
  const int g = l >> 4, c = l & 15;
  const int m0 = blockIdx.y * 128, n0 = blockIdx.x * 128;
  const int wr = (w >> 1) * 64, wc = (w & 1) * 64;

  f32x4 acc[4][4] = {};

  const int srow = w * 32 + (l >> 2);
  const int slc  = ((l & 3) ^ ((l >> 3) & 3)) * 8;
  const unsigned short* Ag = A  + (size_t)(m0 + srow) * KD_ + slc;
  const unsigned short* Bg = Bt + (size_t)(n0 + srow) * KD_ + slc;

  const int sA = (c >> 1) & 3;

  GSTAGE(0, 0);
  GSTAGE(1, 32);
#pragma unroll
  for (int t = 0; t < 32; ++t) GEMM_ITER(t);

#pragma unroll
  for (int i = 0; i < 4; ++i)
#pragma unroll
    for (int j = 0; j < 4; ++j)
#pragma unroll
      for (int r = 0; r < 4; ++r) {
        const int m = m0 + wr + i * 16 + g * 4 + r;
        const int n = n0 + wc + j * 16 + c;
        C[(size_t)m * D_ + n] = acc[i][j][r] + bias[n];
      }
}

// ------------- causal flash attention, no-max-sub softmax -------------
// 3 LDS buffers, 2-deep prefetch, single barrier per kv-tile, counted vmcnt(4).
// Each block processes q-tile pair (p, 15-p): exactly 34 kv-iterations.
__global__ __launch_bounds__(256) void attn_fwd5(
    const unsigned short* __restrict__ Q,   // [BH][S][64] (pre-scaled by 0.18033688)
    const unsigned short* __restrict__ Kg,  // [BH][S][64]
    const unsigned short* __restrict__ Vt,  // [BH][64][S]
    unsigned short* __restrict__ O)         // [B][S][1024] bf16
{
  __shared__ unsigned short Kl[3][64 * 64];
  __shared__ unsigned short Vl[3][64 * 64];

  const int tid = threadIdx.x;
  const int w = tid >> 6, l = tid & 63;
  const int q32 = l & 31, hi = l >> 5;

  // XCD-chunked swizzle: all 8 pair-blocks of one bh land on one XCD.
  const int raw = blockIdx.y * 8 + blockIdx.x;         // 0..511
  const int work = (raw & 7) * 64 + (raw >> 3);
  const int bh = work >> 3;
  const int p  = work & 7;
  const int q0A = p * 128;
  const int q0B = (15 - p) * 128;
  const int nA = 2 * (p + 1);                          // runtime
  // total = nA + nB = 34 always (compile-time)

  const unsigned short* Kbh = Kg + (size_t)bh * (S_ * HD_);
  const unsigned short* Vbh = Vt + (size_t)bh * (HD_ * S_);

  bf16x8 qf[4];
  auto loadQ = [&](int q0) {
    const unsigned short* Qrow = Q + ((size_t)bh * S_ + q0 + w * 32 + q32) * HD_ + hi * 8;
#pragma unroll
    for (int s = 0; s < 4; ++s) qf[s] = ldfrag(Qrow + s * 16);
  };

  f32x16 od0 = {}, od1 = {};
  float lrun = 0.f;

  const int krow = w * 16 + (l >> 3);
  const int slc = ((l & 7) ^ (l >> 3)) * 8;  // inverse-swizzled source chunk

#define LDSOFF(r, ch) ((r) * 64 + (((ch) ^ ((r) & 7)) << 3))

#define STAGE(buf, tile) do {                                                   \
    const int k0s = (tile) * 64;                                                \
    gload16(Kbh + (size_t)(k0s + krow) * HD_ + slc,     &Kl[buf][(w*16)*64]);   \
    gload16(Kbh + (size_t)(k0s + krow + 8) * HD_ + slc, &Kl[buf][(w*16+8)*64]); \
    gload16(Vbh + (size_t)krow * S_ + k0s + slc,        &Vl[buf][(w*16)*64]);   \
    gload16(Vbh + (size_t)(krow + 8) * S_ + k0s + slc,  &Vl[buf][(w*16+8)*64]); \
  } while (0)

  auto epilogue = [&](int q0) {
    const float rl = 1.0f / lrun;
    const int bb = bh >> 4, hh = bh & 15;
    const int sq = q0 + w * 32 + q32;
    unsigned short* Orow = O + ((size_t)bb * S_ + sq) * D_ + hh * HD_;
#pragma unroll
    for (int rr = 0; rr < 4; ++rr) {
      uint2 v0, v1;
      v0.x = cvtpk(od0[4 * rr] * rl,     od0[4 * rr + 1] * rl);
      v0.y = cvtpk(od0[4 * rr + 2] * rl, od0[4 * rr + 3] * rl);
      *reinterpret_cast<uint2*>(Orow + 8 * rr + 4 * hi) = v0;
      v1.x = cvtpk(od1[4 * rr] * rl,     od1[4 * rr + 1] * rl);
      v1.y = cvtpk(od1[4 * rr + 2] * rl, od1[4 * rr + 3] * rl);
      *reinterpret_cast<uint2*>(Orow + 32 + 8 * rr + 4 * hi) = v1;
    }
  };

  loadQ(q0A);
  STAGE(0, 0);
  STAGE(1, 1);
  int cur = 0;           // idx % 3
  int q0 = q0A;

  for (int idx = 0; idx < 34; ++idx) {
    const int kv = (idx < nA) ? idx : idx - nA;
    const int k0 = kv * 64;
    if (idx != 33) asm volatile("s_waitcnt vmcnt(4) lgkmcnt(0)" ::: "memory");
    else           asm volatile("s_waitcnt vmcnt(0) lgkmcnt(0)" ::: "memory");
    __builtin_amdgcn_s_barrier();
    __builtin_amdgcn_sched_barrier(0);

    // 2-ahead prefetch into buf (idx+2)%3 (its readers finished at iter idx-1).
    if (idx + 2 < 34) {
      const int i2 = idx + 2;
      const int nkv = (i2 < nA) ? i2 : i2 - nA;
      int sb = cur + 2; if (sb >= 3) sb -= 3;
      STAGE(sb, nkv);
    }

    const int wqmin = q0 + w * 32;
    if (k0 <= wqmin + 31) {   // wave-tile not fully masked
      const bool live1 = (k0 + 32 <= wqmin + 31);
      const unsigned short* Kb_ = &Kl[cur][0];
      const unsigned short* Vb_ = &Vl[cur][0];

      // ---- S^T = K x Q^T ----
      f32x16 st0 = {}, st1 = {};
      __builtin_amdgcn_s_setprio(1);
#pragma unroll
      for (int s = 0; s < 4; ++s) {
        bf16x8 kf = ldfrag(Kb_ + LDSOFF(q32, 2 * s + hi));
        st0 = __builtin_amdgcn_mfma_f32_32x32x16_bf16(kf, qf[s], st0, 0, 0, 0);
      }
      if (live1) {
#pragma unroll
        for (int s = 0; s < 4; ++s) {
          bf16x8 kf = ldfrag(Kb_ + LDSOFF(32 + q32, 2 * s + hi));
          st1 = __builtin_amdgcn_mfma_f32_32x32x16_bf16(kf, qf[s], st1, 0, 0, 0);
        }
      }
      __builtin_amdgcn_s_setprio(0);

      // ---- causal mask (diagonal region only) ----
      if (k0 + 63 > wqmin) {
        const int rel = wqmin + q32 - k0;
#pragma unroll
        for (int r = 0; r < 16; ++r) {
          const int kva = (r & 3) + 8 * (r >> 2) + 4 * hi;
          if (kva > rel) st0[r] = -1e30f;
        }
        if (live1) {
#pragma unroll
          for (int r = 0; r < 16; ++r) {
            const int kva = (r & 3) + 8 * (r >> 2) + 4 * hi;
            if (kva + 32 > rel) st1[r] = -1e30f;
          }
        }
      }

      // ---- p = exp2(st) directly; row-sum via packed f32 adds ----
      float2 e0[8], e1[8];
#pragma unroll
      for (int r = 0; r < 8; ++r) {
        e0[r].x = __builtin_amdgcn_exp2f(st0[2 * r]);
        e0[r].y = __builtin_amdgcn_exp2f(st0[2 * r + 1]);
      }
      float2 a0 = pkadd2(pkadd2(e0[0], e0[1]), pkadd2(e0[2], e0[3]));
      float2 a1 = pkadd2(pkadd2(e0[4], e0[5]), pkadd2(e0[6], e0[7]));
      float2 asum = pkadd2(a0, a1);
      if (live1) {
#pragma unroll
        for (int r = 0; r < 8; ++r) {
          e1[r].x = __builtin_amdgcn_exp2f(st1[2 * r]);
          e1[r].y = __builtin_amdgcn_exp2f(st1[2 * r + 1]);
        }
        float2 b0 = pkadd2(pkadd2(e1[0], e1[1]), pkadd2(e1[2], e1[3]));
        float2 b1 = pkadd2(pkadd2(e1[4], e1[5]), pkadd2(e1[6], e1[7]));
        asum = pkadd2(asum, pkadd2(b0, b1));
      }
      float ps = asum.x + asum.y;
      ps += __shfl_xor(ps, 32);
      lrun += ps;

      // ---- P -> bf16 A-frags via cvt_pk + permlane32_swap ----
      unsigned int W0, W1, W2, W3, W4, W5, W6, W7;
      W0 = cvtpk(e0[0].x, e0[0].y); W1 = cvtpk(e0[1].x, e0[1].y);
      W2 = cvtpk(e0[2].x, e0[2].y); W3 = cvtpk(e0[3].x, e0[3].y);
      W4 = cvtpk(e0[4].x, e0[4].y); W5 = cvtpk(e0[5].x, e0[5].y);
      W6 = cvtpk(e0[6].x, e0[6].y); W7 = cvtpk(e0[7].x, e0[7].y);
      plswap(W0, W2); plswap(W1, W3); plswap(W4, W6); plswap(W5, W7);
      const bf16x8 pa0 = mkfrag(W0, W1, W2, W3);
      const bf16x8 pa1 = mkfrag(W4, W5, W6, W7);
      bf16x8 pa2, pa3;
      if (live1) {
        W0 = cvtpk(e1[0].x, e1[0].y); W1 = cvtpk(e1[1].x, e1[1].y);
        W2 = cvtpk(e1[2].x, e1[2].y); W3 = cvtpk(e1[3].x, e1[3].y);
        W4 = cvtpk(e1[4].x, e1[4].y); W5 = cvtpk(e1[5].x, e1[5].y);
        W6 = cvtpk(e1[6].x, e1[6].y); W7 = cvtpk(e1[7].x, e1[7].y);
        plswap(W0, W2); plswap(W1, W3); plswap(W4, W6); plswap(W5, W7);
        pa2 = mkfrag(W0, W1, W2, W3);
        pa3 = mkfrag(W4, W5, W6, W7);
      }

      // ---- O^T += V^T x P^T ----
      __builtin_amdgcn_s_setprio(1);
#pragma unroll
      for (int s = 0; s < 2; ++s) {
        const bf16x8 pa = (s == 0) ? pa0 : pa1;
        bf16x8 vf = ldfrag(Vb_ + LDSOFF(q32, 2 * s + hi));
        od0 = __builtin_amdgcn_mfma_f32_32x32x16_bf16(vf, pa, od0, 0, 0, 0);
        bf16x8 vg = ldfrag(Vb_ + LDSOFF(32 + q32, 2 * s + hi));
        od1 = __builtin_amdgcn_mfma_f32_32x32x16_bf16(vg, pa, od1, 0, 0, 0);
      }
      if (live1) {
#pragma unroll
        for (int s = 2; s < 4; ++s) {
          const bf16x8 pa = (s == 2) ? pa2 : pa3;
          bf16x8 vf = ldfrag(Vb_ + LDSOFF(q32, 2 * s + hi));
          od0 = __builtin_amdgcn_mfma_f32_32x32x16_bf16(vf, pa, od0, 0, 0, 0);
          bf16x8 vg = ldfrag(Vb_ + LDSOFF(32 + q32, 2 * s + hi));
          od1 = __builtin_amdgcn_mfma_f32_32x32x16_bf16(vg, pa, od1, 0, 0, 0);
        }
      }
      __builtin_amdgcn_s_setprio(0);
    }

    // transition A -> B (register-only; no LDS hazard)
    if (idx == nA - 1) {
      epilogue(q0A);
      loadQ(q0B);
      od0 = {}; od1 = {};
      lrun = 0.f;
      q0 = q0B;
    }
    cur = (cur == 2) ? 0 : cur + 1;
  }

  epilogue(q0B);
#undef STAGE
#undef LDSOFF
}

extern "C" void kernel_launch(void* const* d_in, const int* in_sizes, int n_in,
                              void* d_out, int out_size, void* d_ws, size_t ws_size,
                              hipStream_t stream) {
  (void)in_sizes; (void)n_in; (void)out_size; (void)ws_size;
  const float* x     = (const float*)d_in[0];
  const float* w_in  = (const float*)d_in[1];
  const float* b_in  = (const float*)d_in[2];
  const float* w_out = (const float*)d_in[3];
  const float* b_out = (const float*)d_in[4];
  float* out = (float*)d_out;
  char* ws = (char*)d_ws;
  const size_t MB = 1024 * 1024;
  unsigned short* xb     = (unsigned short*)(ws);             // 16MB
  unsigned short* w_inb  = (unsigned short*)(ws + 16 * MB);   // 6MB
  unsigned short* w_outb = (unsigned short*)(ws + 22 * MB);   // 2MB
  unsigned short* Qb     = (unsigned short*)(ws + 24 * MB);   // 16MB
  unsigned short* Kb     = (unsigned short*)(ws + 40 * MB);   // 16MB
  unsigned short* Vt     = (unsigned short*)(ws + 56 * MB);   // 16MB (transposed V)
  unsigned short* Ob     = (unsigned short*)(ws + 72 * MB);   // 16MB

  xconv<<<4096, 256, 0, stream>>>(x, xb);
  wtrans<<<dim3(96, 32), 256, 0, stream>>>(w_in, w_inb, 1024, 3072);
  wtrans<<<dim3(32, 32), 256, 0, stream>>>(w_out, w_outb, 1024, 1024);
  qkv_gemm<<<dim3(24, 64), 256, 0, stream>>>(xb, w_inb, b_in, Qb, Kb, Vt);
  attn_fwd5<<<dim3(8, 64), 256, 0, stream>>>(Qb, Kb, Vt, Ob);
  out_gemm<<<dim3(8, 64), 256, 0, stream>>>(Ob, w_outb, b_out, out);
}